// Round 6
// baseline (150.258 us; speedup 1.0000x reference)
//
#include <hip/hip_runtime.h>
#include <hip/hip_bf16.h>

// Problem constants
#define L_DIM 128
#define N_DIM 32
#define C_DIM 128
#define K_DIM 128   // DIM_MLP
#define OUT_DIM 128

typedef __attribute__((ext_vector_type(8))) short short8;
typedef __attribute__((ext_vector_type(4))) float float4v;

static __device__ __forceinline__ short bf16_bits(float f) {
    __bf16 h = (__bf16)f;   // RNE
    return __builtin_bit_cast(short, h);
}

// ---------------------------------------------------------------------------
// Kernel 1: precompute.
//   blocks 0..511 : 8 flat rows each; weight tiles double-buffered in LDS.
//     P = x·W1a ; Q = x·W1b + b1 ; V = relu(x·Vw1+vb1)·Vw2 + vb2
//   blocks 512..575: W2s = attn_w2 swizzled into bf16 MFMA fragment order
// ---------------------------------------------------------------------------
__global__ __launch_bounds__(256) void k_pre(
    const float* __restrict__ x,
    const float* __restrict__ attn_w1, const float* __restrict__ attn_b1,
    const float* __restrict__ attn_w2,
    const float* __restrict__ value_w1, const float* __restrict__ value_b1,
    const float* __restrict__ value_w2, const float* __restrict__ value_b2,
    float* __restrict__ P, float* __restrict__ Q, float* __restrict__ V,
    short* __restrict__ W2s)
{
    int bid = blockIdx.x;
    int tid = threadIdx.x;
    if (bid >= 512) {
        // W2 fragment swizzle: e = ((((ct*4+mi)*4+quad)*16+col)*8+idx)
        // element = attn_w2[k][c], k = quad*8+32*mi+idx, c = ct*16+col.
        // (Same mapping serves as the A-operand W2^T fragment in k_main.)
        int e = (bid - 512) * 256 + tid;              // 64*256 = 16384 elems
        int idx  = e & 7;
        int colr = (e >> 3) & 15;
        int quad = (e >> 7) & 3;
        int mi   = (e >> 9) & 3;
        int ct   = e >> 11;
        int k = quad * 8 + 32 * mi + idx;
        int c = ct * 16 + colr;
        W2s[e] = bf16_bits(attn_w2[k * OUT_DIM + c]);
        return;
    }

    __shared__ float xs[8][C_DIM];           // 4 KB
    __shared__ float hvs[8][K_DIM];          // 4 KB
    __shared__ float Wt[2][3 * 2048];        // 48 KB: dbuf 16-row x 3-matrix tiles

    int r0 = bid * 8;                        // first flat row (i*N+b)

    {   // stage 8 x-rows: 1024 floats = 256 float4
        int row = tid >> 5, c4 = (tid & 31) * 4;
        *(float4v*)&xs[row][c4] = *(const float4v*)(x + (r0 + row) * C_DIM + c4);
    }
    {   // stage weight tile 0 (c-rows 0..15 of W1a, W1b, Vw1)
        #pragma unroll
        for (int t = 0; t < 6; ++t) {
            int e = t * 256 + tid;                    // 1536 float4
            int mat = e >> 9, rw = (e >> 5) & 15, k4 = (e & 31) * 4;
            const float* src = (mat == 0) ? attn_w1 + rw * K_DIM + k4
                             : (mat == 1) ? attn_w1 + (C_DIM + rw) * K_DIM + k4
                                          : value_w1 + rw * K_DIM + k4;
            *(float4v*)&Wt[0][mat * 2048 + rw * K_DIM + k4] = *(const float4v*)src;
        }
    }
    __syncthreads();

    int ks   = tid & 127;      // output column k (or c)
    int half = tid >> 7;       // rows 0-3 vs 4-7

    float pa[4] = {0,0,0,0}, qa[4] = {0,0,0,0}, ha[4] = {0,0,0,0};

    for (int ct = 0; ct < 8; ++ct) {
        int cur = ct & 1;
        float4v nw[6];
        if (ct < 7) {
            #pragma unroll
            for (int t = 0; t < 6; ++t) {
                int e = t * 256 + tid;
                int mat = e >> 9, rw = (e >> 5) & 15, k4 = (e & 31) * 4;
                int row = (ct + 1) * 16 + rw;
                const float* src = (mat == 0) ? attn_w1 + row * K_DIM + k4
                                 : (mat == 1) ? attn_w1 + (C_DIM + row) * K_DIM + k4
                                              : value_w1 + row * K_DIM + k4;
                nw[t] = *(const float4v*)src;
            }
        }
        #pragma unroll
        for (int g = 0; g < 4; ++g) {
            float4v xr4[4];
            #pragma unroll
            for (int r = 0; r < 4; ++r)
                xr4[r] = *(const float4v*)&xs[half * 4 + r][ct * 16 + g * 4];
            #pragma unroll
            for (int u = 0; u < 4; ++u) {
                int cc = g * 4 + u;
                float wa = Wt[cur][cc * K_DIM + ks];
                float wb = Wt[cur][2048 + cc * K_DIM + ks];
                float wv = Wt[cur][4096 + cc * K_DIM + ks];
                #pragma unroll
                for (int r = 0; r < 4; ++r) {
                    float xr = xr4[r][u];
                    pa[r] = fmaf(xr, wa, pa[r]);
                    qa[r] = fmaf(xr, wb, qa[r]);
                    ha[r] = fmaf(xr, wv, ha[r]);
                }
            }
        }
        if (ct < 7) {
            #pragma unroll
            for (int t = 0; t < 6; ++t) {
                int e = t * 256 + tid;
                int mat = e >> 9, rw = (e >> 5) & 15, k4 = (e & 31) * 4;
                *(float4v*)&Wt[cur ^ 1][mat * 2048 + rw * K_DIM + k4] = nw[t];
            }
        }
        __syncthreads();
    }

    float b1 = attn_b1[ks], vb1 = value_b1[ks];
    #pragma unroll
    for (int r = 0; r < 4; ++r) {
        int rr = r0 + half * 4 + r;
        int i = rr >> 5, bb = rr & 31;                 // rr = i*N + b
        P[(bb * L_DIM + i) * K_DIM + ks] = pa[r];
        Q[(bb * L_DIM + i) * K_DIM + ks] = qa[r] + b1;
        hvs[half * 4 + r][ks] = fmaxf(ha[r] + vb1, 0.f);
    }

    {   // stage Vw2 tile 0 (k-rows 0..31)
        #pragma unroll
        for (int t = 0; t < 4; ++t) {
            int e = t * 256 + tid;                    // 1024 float4
            int rw = e >> 5, k4 = (e & 31) * 4;
            *(float4v*)&Wt[0][rw * K_DIM + k4] =
                *(const float4v*)(value_w2 + rw * OUT_DIM + k4);
        }
    }
    __syncthreads();

    float va[4] = {0,0,0,0};
    for (int kt = 0; kt < 4; ++kt) {
        int cur = kt & 1;
        float4v nw[4];
        if (kt < 3) {
            #pragma unroll
            for (int t = 0; t < 4; ++t) {
                int e = t * 256 + tid;
                int rw = e >> 5, k4 = (e & 31) * 4;
                nw[t] = *(const float4v*)
                    (value_w2 + ((kt + 1) * 32 + rw) * OUT_DIM + k4);
            }
        }
        #pragma unroll
        for (int g = 0; g < 8; ++g) {
            float4v hv4[4];
            #pragma unroll
            for (int r = 0; r < 4; ++r)
                hv4[r] = *(const float4v*)&hvs[half * 4 + r][kt * 32 + g * 4];
            #pragma unroll
            for (int u = 0; u < 4; ++u) {
                float w = Wt[cur][(g * 4 + u) * K_DIM + ks];
                #pragma unroll
                for (int r = 0; r < 4; ++r)
                    va[r] = fmaf(hv4[r][u], w, va[r]);
            }
        }
        if (kt < 3) {
            #pragma unroll
            for (int t = 0; t < 4; ++t) {
                int e = t * 256 + tid;
                int rw = e >> 5, k4 = (e & 31) * 4;
                *(float4v*)&Wt[cur ^ 1][rw * K_DIM + k4] = nw[t];
            }
        }
        __syncthreads();
    }
    float vb2 = value_b2[ks];
    #pragma unroll
    for (int r = 0; r < 4; ++r) {
        int rr = r0 + half * 4 + r;
        int i = rr >> 5, bb = rr & 31;
        V[(bb * L_DIM + i) * OUT_DIM + ks] = va[r] + vb2;
    }
}

// ---------------------------------------------------------------------------
// Kernel 2: fused pairwise-MLP + j-reduce, operand-swapped MFMA.
//   grid 1024 x 256 thr; b = blk&31 (XCD-local), itile = blk>>5.
//   4 waves, wave w owns i = itile*4+w (zero build duplication).
//   D = W2^T · h^T  (A = W2^T frag, 128 VGPR resident; B = h frag built
//   in-register from fp32 P (resident) + Q (dbuf LDS)).
//   D rows = c (4 consecutive per lane) -> V is float4 loads; b2 is folded
//   into the accumulator init (out = sum_j (D + b2) * V).
//   j-reduce = 4 xor-shuffles over cols at the end.
// ---------------------------------------------------------------------------
#define QSTR 132   // 128 + 4-float pad

__global__ __launch_bounds__(256, 1) void k_main(
    const float* __restrict__ P, const float* __restrict__ Q,
    const float* __restrict__ V, const short* __restrict__ W2s,
    const float* __restrict__ attn_b2, float* __restrict__ out)
{
    __shared__ float Qb[2][16 * QSTR];       // 16.9 KB double-buffered Q tile

    int blk   = blockIdx.x;
    int b     = blk & 31;                    // XCD-local: 4 b-values per XCD
    int itile = blk >> 5;
    int tid   = threadIdx.x;
    int wave  = tid >> 6;
    int lane  = tid & 63;
    int quad  = lane >> 4;
    int col   = lane & 15;
    int i_g   = itile * 4 + wave;

    // A-operand: W2^T fragments, full residency (128 VGPR)
    short8 bfrag[8][4];
    const short8* w2p = (const short8*)W2s;
    #pragma unroll
    for (int ct = 0; ct < 8; ++ct)
        #pragma unroll
        for (int mi = 0; mi < 4; ++mi)
            bfrag[ct][mi] = w2p[((ct * 4 + mi) * 4 + quad) * 16 + col];

    // P fp32 resident (this wave's i), k = quad*8 + mi*32 + t
    float4v p[4][2];
    const float* Pr = P + (size_t)(b * L_DIM + i_g) * K_DIM;
    #pragma unroll
    for (int mi = 0; mi < 4; ++mi) {
        p[mi][0] = *(const float4v*)(Pr + quad * 8 + mi * 32);
        p[mi][1] = *(const float4v*)(Pr + quad * 8 + mi * 32 + 4);
    }

    // b2 folded into accumulator init: lane's c = ct*16 + quad*4 + rr
    float4v b2c[8];
    #pragma unroll
    for (int ct = 0; ct < 8; ++ct)
        b2c[ct] = *(const float4v*)(attn_b2 + ct * 16 + quad * 4);

    // Q staging: 2048 floats / 256 thr = 8 floats each
    int srow = tid >> 4;
    int sc8  = (tid & 15) * 8;
    const float* Qbase = Q + (size_t)b * L_DIM * K_DIM;
    const float* Vbase = V + (size_t)b * L_DIM * OUT_DIM;

    {
        const float* qp = Qbase + srow * K_DIM + sc8;
        *(float4v*)&Qb[0][srow * QSTR + sc8]     = *(const float4v*)qp;
        *(float4v*)&Qb[0][srow * QSTR + sc8 + 4] = *(const float4v*)(qp + 4);
    }
    __syncthreads();

    float4v acc[8] = {};

    for (int r = 0; r < 8; ++r) {
        int cur = r & 1;

        // next Q tile -> regs (issued early, hides L2 latency)
        float4v nq0, nq1;
        if (r < 7) {
            const float* qp = Qbase + ((r + 1) * 16 + srow) * K_DIM + sc8;
            nq0 = *(const float4v*)qp;
            nq1 = *(const float4v*)(qp + 4);
        }

        // V for this round: lane's j = r*16+col, c = ct*16+quad*4.. (+3)
        const float* Vr = Vbase + (size_t)(r * 16 + col) * OUT_DIM + quad * 4;
        float4v vv[8];
        #pragma unroll
        for (int ct = 0; ct < 8; ++ct)
            vv[ct] = *(const float4v*)(Vr + ct * 16);

        // build B-operand h frags: h[j=col][k=quad*8+mi*32+t] = relu(P+Q)
        short8 hf[4];
        #pragma unroll
        for (int mi = 0; mi < 4; ++mi) {
            const float* qc = &Qb[cur][col * QSTR + quad * 8 + mi * 32];
            float4v q0 = *(const float4v*)qc;
            float4v q1 = *(const float4v*)(qc + 4);
            float4v h0 = __builtin_elementwise_max(p[mi][0] + q0, (float4v)0.f);
            float4v h1 = __builtin_elementwise_max(p[mi][1] + q1, (float4v)0.f);
            short8 a;
            #pragma unroll
            for (int t = 0; t < 4; ++t) {
                a[t]     = bf16_bits(h0[t]);
                a[t + 4] = bf16_bits(h1[t]);
            }
            hf[mi] = a;
        }

        // D = W2^T · h^T + b2 ; then acc += D * V  (j-partial, per lane)
        #pragma unroll
        for (int ct = 0; ct < 8; ++ct) {
            float4v c4 = b2c[ct];
            #pragma unroll
            for (int mi = 0; mi < 4; ++mi)
                c4 = __builtin_amdgcn_mfma_f32_16x16x32_bf16(
                        bfrag[ct][mi], hf[mi], c4, 0, 0, 0);
            acc[ct] += c4 * vv[ct];
        }

        if (r < 7) {
            *(float4v*)&Qb[cur ^ 1][srow * QSTR + sc8]     = nq0;
            *(float4v*)&Qb[cur ^ 1][srow * QSTR + sc8 + 4] = nq1;
        }
        __syncthreads();
    }

    // j-reduce across the 16 cols; then col 0 of each quad stores float4
    #pragma unroll
    for (int ct = 0; ct < 8; ++ct) {
        float4v t = acc[ct];
        #pragma unroll
        for (int rr = 0; rr < 4; ++rr) {
            t[rr] += __shfl_xor(t[rr], 1, 64);
            t[rr] += __shfl_xor(t[rr], 2, 64);
            t[rr] += __shfl_xor(t[rr], 4, 64);
            t[rr] += __shfl_xor(t[rr], 8, 64);
        }
        if (col == 0)
            *(float4v*)(out + (size_t)(i_g * N_DIM + b) * OUT_DIM
                        + ct * 16 + quad * 4) = t;
    }
}

// ---------------------------------------------------------------------------
extern "C" void kernel_launch(void* const* d_in, const int* in_sizes, int n_in,
                              void* d_out, int out_size, void* d_ws, size_t ws_size,
                              hipStream_t stream)
{
    const float* x        = (const float*)d_in[0];
    const float* attn_w1  = (const float*)d_in[1];
    const float* attn_b1  = (const float*)d_in[2];
    const float* attn_w2  = (const float*)d_in[3];
    const float* attn_b2  = (const float*)d_in[4];
    const float* value_w1 = (const float*)d_in[5];
    const float* value_b1 = (const float*)d_in[6];
    const float* value_w2 = (const float*)d_in[7];
    const float* value_b2 = (const float*)d_in[8];
    float* out = (float*)d_out;

    // Workspace (floats): P 512K | Q 512K | V 512K | W2s(bf16) 16384 shorts
    float* ws = (float*)d_ws;
    float* P  = ws;
    float* Q  = ws + 524288;
    float* V  = ws + 1048576;
    short* W2s = (short*)(ws + 1572864);

    k_pre<<<576, 256, 0, stream>>>(x, attn_w1, attn_b1, attn_w2,
                                   value_w1, value_b1, value_w2, value_b2,
                                   P, Q, V, W2s);
    k_main<<<1024, 256, 0, stream>>>(P, Q, V, W2s, attn_b2, out);
}

// Round 7
// 139.406 us; speedup vs baseline: 1.0778x; 1.0778x over previous
//
#include <hip/hip_runtime.h>
#include <hip/hip_bf16.h>

// Problem constants
#define L_DIM 128
#define N_DIM 32
#define C_DIM 128
#define K_DIM 128   // DIM_MLP
#define OUT_DIM 128

typedef __attribute__((ext_vector_type(8))) short short8;
typedef __attribute__((ext_vector_type(4))) float float4v;

static __device__ __forceinline__ short bf16_bits(float f) {
    __bf16 h = (__bf16)f;   // RNE
    return __builtin_bit_cast(short, h);
}

// ---------------------------------------------------------------------------
// Kernel 1: precompute (occupancy-first: 1024 blocks x 4 rows, no weight LDS;
//   weights are L2-resident broadcasts, 24 loads in flight per thread).
//     P = x·W1a ; Q = x·W1b + b1 ; V = relu(x·Vw1+vb1)·Vw2 + vb2
//   blocks 1024..1087: W2s = attn_w2 swizzled into bf16 MFMA B-fragment order
// ---------------------------------------------------------------------------
__global__ __launch_bounds__(256) void k_pre(
    const float* __restrict__ x,
    const float* __restrict__ attn_w1, const float* __restrict__ attn_b1,
    const float* __restrict__ attn_w2,
    const float* __restrict__ value_w1, const float* __restrict__ value_b1,
    const float* __restrict__ value_w2, const float* __restrict__ value_b2,
    float* __restrict__ P, float* __restrict__ Q, float* __restrict__ V,
    short* __restrict__ W2s)
{
    int bid = blockIdx.x;
    int tid = threadIdx.x;
    if (bid >= 1024) {
        // W2 swizzle: e = ((((ct*4+mi)*4+quad)*16+col)*8+idx)
        // element = attn_w2[k][c], k = quad*8+32*mi+idx, c = ct*16+col
        int e = (bid - 1024) * 256 + tid;             // 64*256 = 16384 elems
        int idx  = e & 7;
        int colr = (e >> 3) & 15;
        int quad = (e >> 7) & 3;
        int mi   = (e >> 9) & 3;
        int ct   = e >> 11;
        int k = quad * 8 + 32 * mi + idx;
        int c = ct * 16 + colr;
        W2s[e] = bf16_bits(attn_w2[k * OUT_DIM + c]);
        return;
    }

    __shared__ float xs[4][C_DIM];           // 2 KB
    __shared__ float hvs[4][K_DIM];          // 2 KB

    int r0 = bid * 4;                        // first flat row (i*N+b)

    if (tid < 128) {                         // stage 4 x-rows (128 float4)
        int row = tid >> 5, c4 = (tid & 31) * 4;
        *(float4v*)&xs[row][c4] = *(const float4v*)(x + (r0 + row) * C_DIM + c4);
    }
    __syncthreads();

    int ks   = tid & 127;      // output column k (or c)
    int half = tid >> 7;       // rows 0-1 vs 2-3

    const float* wa_p = attn_w1 + ks;
    const float* wb_p = attn_w1 + C_DIM * K_DIM + ks;
    const float* wv_p = value_w1 + ks;

    float pa0 = 0, pa1 = 0, qa0 = 0, qa1 = 0, ha0 = 0, ha1 = 0;
    #pragma unroll 8
    for (int c = 0; c < C_DIM; ++c) {
        float wa = wa_p[c * K_DIM];
        float wb = wb_p[c * K_DIM];
        float wv = wv_p[c * K_DIM];
        float x0 = xs[half * 2][c];
        float x1 = xs[half * 2 + 1][c];
        pa0 = fmaf(x0, wa, pa0); pa1 = fmaf(x1, wa, pa1);
        qa0 = fmaf(x0, wb, qa0); qa1 = fmaf(x1, wb, qa1);
        ha0 = fmaf(x0, wv, ha0); ha1 = fmaf(x1, wv, ha1);
    }

    float b1 = attn_b1[ks], vb1 = value_b1[ks];
    {
        int rr0 = r0 + half * 2;
        int i0 = rr0 >> 5, b0 = rr0 & 31;             // rr = i*N + b
        int i1 = (rr0 + 1) >> 5, b1i = (rr0 + 1) & 31;
        P[(b0 * L_DIM + i0) * K_DIM + ks] = pa0;
        P[(b1i * L_DIM + i1) * K_DIM + ks] = pa1;
        Q[(b0 * L_DIM + i0) * K_DIM + ks] = qa0 + b1;
        Q[(b1i * L_DIM + i1) * K_DIM + ks] = qa1 + b1;
        hvs[half * 2][ks]     = fmaxf(ha0 + vb1, 0.f);
        hvs[half * 2 + 1][ks] = fmaxf(ha1 + vb1, 0.f);
    }
    __syncthreads();

    const float* w2_p = value_w2 + ks;
    float va0 = 0, va1 = 0;
    #pragma unroll 8
    for (int k = 0; k < K_DIM; ++k) {
        float w = w2_p[k * OUT_DIM];
        va0 = fmaf(hvs[half * 2][k], w, va0);
        va1 = fmaf(hvs[half * 2 + 1][k], w, va1);
    }
    float vb2 = value_b2[ks];
    {
        int rr0 = r0 + half * 2;
        int i0 = rr0 >> 5, b0 = rr0 & 31;
        int i1 = (rr0 + 1) >> 5, b1i = (rr0 + 1) & 31;
        V[(b0 * L_DIM + i0) * OUT_DIM + ks] = va0 + vb2;
        V[(b1i * L_DIM + i1) * OUT_DIM + ks] = va1 + vb2;
    }
}

// ---------------------------------------------------------------------------
// Kernel 2: fused pairwise-MLP + j-reduce, split-K across wave quarters.
//   grid 1024 x 512 thr; b = blk&31 (XCD-local), itile = blk>>5.
//   8 waves = ipair(2 i's) x kquad(32 k's). Resident state is R5-class
//   (proven no-spill): bfrag[8]=32 VGPR, p[2]=16, acc scalars.
//   Per round (16 j's): Q tile dbuf LDS; each wave builds h for its own
//   k-slice ONCE (no duplication), 16 K=32-partial MFMAs, V-scale (linear
//   => k-partials valid), in-loop sv on kq==0. One barrier/round.
//   End: xor16/32 j-reduce -> LDS kq-combine -> fold b2*Sv -> store.
// ---------------------------------------------------------------------------
#define QSTR 132   // 128 + 4-float pad

__global__ __launch_bounds__(512) void k_main(
    const float* __restrict__ P, const float* __restrict__ Q,
    const float* __restrict__ V, const short* __restrict__ W2s,
    const float* __restrict__ attn_b2, float* __restrict__ out)
{
    __shared__ float Qb[2][16 * QSTR];       // 16.9 KB double-buffered Q tile
    __shared__ float comb[4 * 128 * 4];      // [i_l][c][kq] 8 KB
    __shared__ float svl[128];

    int blk   = blockIdx.x;
    int b     = blk & 31;                    // XCD-local: 4 b-values per XCD
    int itile = blk >> 5;
    int tid   = threadIdx.x;
    int wave  = tid >> 6;
    int lane  = tid & 63;
    int quad  = lane >> 4;
    int col   = lane & 15;
    int ip    = wave & 1;                    // i-pair
    int kq    = wave >> 1;                   // k-quarter (0..3)
    int i0    = itile * 4 + ip * 2;

    // B-frags: W2 for this wave's k-slice, all 8 c-tiles (32 VGPR)
    short8 bfrag[8];
    const short8* w2p = (const short8*)W2s;
    #pragma unroll
    for (int ct = 0; ct < 8; ++ct)
        bfrag[ct] = w2p[((ct * 4 + kq) * 4 + quad) * 16 + col];

    // P slices: 2 i's x 8 floats at k = kq*32 + quad*8 + idx (16 VGPR)
    float4v p[2][2];
    #pragma unroll
    for (int il = 0; il < 2; ++il) {
        const float* Pr = P + (size_t)(b * L_DIM + i0 + il) * K_DIM
                        + kq * 32 + quad * 8;
        p[il][0] = *(const float4v*)Pr;
        p[il][1] = *(const float4v*)(Pr + 4);
    }

    // Q staging: 512 thr x 1 float4 = full 16x128 tile
    int srow = tid >> 5;             // 0..15
    int sc4  = (tid & 31) * 4;
    const float* Qbase = Q + (size_t)b * L_DIM * K_DIM;
    const float* Vbase = V + (size_t)b * L_DIM * OUT_DIM;

    *(float4v*)&Qb[0][srow * QSTR + sc4] =
        *(const float4v*)(Qbase + srow * K_DIM + sc4);
    __syncthreads();

    float acc[2][8] = {};
    float sv[8]     = {};

    for (int r = 0; r < 8; ++r) {
        int cur = r & 1;

        // next Q tile -> regs (overlaps compute)
        float4v nq;
        if (r < 7)
            nq = *(const float4v*)(Qbase + ((r + 1) * 16 + srow) * K_DIM + sc4);

        // V: 32 scalars (L2-hot), issued before the build/MFMA chain
        const float* Vr = Vbase + (size_t)(r * 16 + quad * 4) * OUT_DIM + col;
        float vv[4][8];
        #pragma unroll
        for (int rr = 0; rr < 4; ++rr)
            #pragma unroll
            for (int ct = 0; ct < 8; ++ct)
                vv[rr][ct] = Vr[rr * OUT_DIM + ct * 16];

        // build h-frags for this k-slice ONCE: h[j=col][k] = relu(P+Q)
        const float* qc = &Qb[cur][col * QSTR + kq * 32 + quad * 8];
        float4v q0 = *(const float4v*)qc;
        float4v q1 = *(const float4v*)(qc + 4);
        short8 hf[2];
        #pragma unroll
        for (int il = 0; il < 2; ++il) {
            float4v h0 = __builtin_elementwise_max(p[il][0] + q0, (float4v)0.f);
            float4v h1 = __builtin_elementwise_max(p[il][1] + q1, (float4v)0.f);
            short8 a;
            #pragma unroll
            for (int t = 0; t < 4; ++t) {
                a[t]     = bf16_bits(h0[t]);
                a[t + 4] = bf16_bits(h1[t]);
            }
            hf[il] = a;
        }

        // K=32-partial MFMAs + V-scaled accumulate (linear in k-partials)
        #pragma unroll
        for (int ct = 0; ct < 8; ++ct) {
            #pragma unroll
            for (int il = 0; il < 2; ++il) {
                float4v c4 = {0.f, 0.f, 0.f, 0.f};
                c4 = __builtin_amdgcn_mfma_f32_16x16x32_bf16(
                        hf[il], bfrag[ct], c4, 0, 0, 0);
                #pragma unroll
                for (int rr = 0; rr < 4; ++rr)
                    acc[il][ct] = fmaf(c4[rr], vv[rr][ct], acc[il][ct]);
            }
            if (kq == 0) {
                #pragma unroll
                for (int rr = 0; rr < 4; ++rr)
                    sv[ct] += vv[rr][ct];
            }
        }

        if (r < 7)
            *(float4v*)&Qb[cur ^ 1][srow * QSTR + sc4] = nq;
        __syncthreads();
    }

    // j-reduce across quads; park k-partials in LDS
    #pragma unroll
    for (int il = 0; il < 2; ++il)
        #pragma unroll
        for (int ct = 0; ct < 8; ++ct) {
            float a = acc[il][ct];
            a += __shfl_xor(a, 16, 64);
            a += __shfl_xor(a, 32, 64);
            if (quad == 0)
                comb[((ip * 2 + il) * 128 + ct * 16 + col) * 4 + kq] = a;
        }
    if (wave == 0) {   // ip==0, kq==0: write Sv
        #pragma unroll
        for (int ct = 0; ct < 8; ++ct) {
            float s = sv[ct];
            s += __shfl_xor(s, 16, 64);
            s += __shfl_xor(s, 32, 64);
            if (quad == 0) svl[ct * 16 + col] = s;
        }
    }
    __syncthreads();

    // final: sum 4 kq partials + b2*Sv, coalesced store
    {
        int il4 = tid >> 7, c = tid & 127;
        float4v cv = *(const float4v*)&comb[(il4 * 128 + c) * 4];
        float tot = cv[0] + cv[1] + cv[2] + cv[3] + attn_b2[c] * svl[c];
        out[(size_t)((itile * 4 + il4) * N_DIM + b) * OUT_DIM + c] = tot;
    }
}

// ---------------------------------------------------------------------------
extern "C" void kernel_launch(void* const* d_in, const int* in_sizes, int n_in,
                              void* d_out, int out_size, void* d_ws, size_t ws_size,
                              hipStream_t stream)
{
    const float* x        = (const float*)d_in[0];
    const float* attn_w1  = (const float*)d_in[1];
    const float* attn_b1  = (const float*)d_in[2];
    const float* attn_w2  = (const float*)d_in[3];
    const float* attn_b2  = (const float*)d_in[4];
    const float* value_w1 = (const float*)d_in[5];
    const float* value_b1 = (const float*)d_in[6];
    const float* value_w2 = (const float*)d_in[7];
    const float* value_b2 = (const float*)d_in[8];
    float* out = (float*)d_out;

    // Workspace (floats): P 512K | Q 512K | V 512K | W2s(bf16) 16384 shorts
    float* ws = (float*)d_ws;
    float* P  = ws;
    float* Q  = ws + 524288;
    float* V  = ws + 1048576;
    short* W2s = (short*)(ws + 1572864);

    k_pre<<<1088, 256, 0, stream>>>(x, attn_w1, attn_b1, attn_w2,
                                    value_w1, value_b1, value_w2, value_b2,
                                    P, Q, V, W2s);
    k_main<<<1024, 512, 0, stream>>>(P, Q, V, W2s, attn_b2, out);
}